// Round 6
// baseline (840.790 us; speedup 1.0000x reference)
//
#include <hip/hip_runtime.h>
#include <cstdint>
#include <cstddef>

#define N_NODES 50000
#define N_EDGES 800000
#define EMB 128
#define EDGE_DIM 16
#define H1_DIM 256
#define BN_EPS 1e-5f

// ---------------- threefry2x32 (JAX-compatible) ----------------
__device__ __forceinline__ uint32_t rotl32(uint32_t v, int n) {
  return (v << n) | (v >> (32 - n));
}

__device__ __forceinline__ void tf_round4(uint32_t& x0, uint32_t& x1,
                                          int r0, int r1, int r2, int r3) {
  x0 += x1; x1 = rotl32(x1, r0); x1 ^= x0;
  x0 += x1; x1 = rotl32(x1, r1); x1 ^= x0;
  x0 += x1; x1 = rotl32(x1, r2); x1 ^= x0;
  x0 += x1; x1 = rotl32(x1, r3); x1 ^= x0;
}

__device__ __forceinline__ void threefry2x32(uint32_t k0, uint32_t k1,
                                             uint32_t& x0, uint32_t& x1) {
  uint32_t k2 = k0 ^ k1 ^ 0x1BD11BDAu;
  x0 += k0; x1 += k1;
  tf_round4(x0, x1, 13, 15, 26, 6);  x0 += k1; x1 += k2 + 1u;
  tf_round4(x0, x1, 17, 29, 16, 24); x0 += k2; x1 += k0 + 2u;
  tf_round4(x0, x1, 13, 15, 26, 6);  x0 += k0; x1 += k1 + 3u;
  tf_round4(x0, x1, 17, 29, 16, 24); x0 += k1; x1 += k2 + 4u;
  tf_round4(x0, x1, 13, 15, 26, 6);  x0 += k2; x1 += k0 + 5u;
}

// ---------------- edge_index canonicalization (int32 vs int64 storage) ----
// (R2==R4 proved int32 storage; kept as cheap insurance.)
__global__ void detect_idx_kernel(const uint32_t* __restrict__ ei, int* __restrict__ flag) {
  __shared__ int nonzero;
  if (threadIdx.x == 0) nonzero = 0;
  __syncthreads();
  if (ei[2 * threadIdx.x + 1] != 0u) atomicAdd(&nonzero, 1);
  __syncthreads();
  if (threadIdx.x == 0) *flag = (nonzero == 0) ? 1 : 0;  // 1 => int64 storage
}

__global__ void convert_idx_kernel(const uint32_t* __restrict__ ei,
                                   const int* __restrict__ flag,
                                   int* __restrict__ idx32) {
  int i = blockIdx.x * blockDim.x + threadIdx.x;
  if (i >= 2 * N_EDGES) return;
  idx32[i] = flag[0] ? (int)ei[2 * i] : (int)ei[i];
}

// ---------------- edge MLP + gather + scatter-add ----------------
__global__ void edge_aggr_kernel(const float* __restrict__ x,
                                 const int* __restrict__ src,
                                 const int* __restrict__ dst,
                                 const float* __restrict__ eattr,
                                 const float* __restrict__ W_edge,
                                 const float* __restrict__ b_edge,
                                 float* __restrict__ aggr) {
  __shared__ float w_lds[EDGE_DIM * EMB];   // 8 KB
  __shared__ float b_lds[EMB];
  __shared__ float attr_lds[2][EDGE_DIM];

  for (int i = threadIdx.x; i < EDGE_DIM * EMB; i += blockDim.x) w_lds[i] = W_edge[i];
  if (threadIdx.x < EMB) b_lds[threadIdx.x] = b_edge[threadIdx.x];
  __syncthreads();

  const int c  = threadIdx.x & (EMB - 1);
  const int el = threadIdx.x >> 7;   // 0 or 1

  for (int e0 = blockIdx.x * 2; e0 < N_EDGES; e0 += gridDim.x * 2) {
    __syncthreads();   // protect attr_lds from previous iteration readers
    if (threadIdx.x < 2 * EDGE_DIM) {
      int ee = e0 + (threadIdx.x >> 4);
      attr_lds[threadIdx.x >> 4][threadIdx.x & 15] = eattr[ee * EDGE_DIM + (threadIdx.x & 15)];
    }
    __syncthreads();

    const int e = e0 + el;
    float acc = b_lds[c];
#pragma unroll
    for (int k = 0; k < EDGE_DIM; k++) acc += attr_lds[el][k] * w_lds[k * EMB + c];
    const int s = src[e];
    const int d = dst[e];
    float m = x[(size_t)s * EMB + c] + acc;
    m = m > 0.0f ? m : 0.0f;
    atomicAdd(&aggr[(size_t)d * EMB + c], m);
  }
}

// ---------------- GEMM1: h1 = ((1+eps)x + aggr) @ W1 + b1 ----------------
__global__ __launch_bounds__(512) void gemm1_kernel(const float* __restrict__ x,
                                                    const float* __restrict__ aggr,
                                                    const float* __restrict__ eps,
                                                    const float* __restrict__ W1,
                                                    const float* __restrict__ b1,
                                                    float* __restrict__ h1) {
  __shared__ float w_lds[EMB * H1_DIM];   // 128 KB
  __shared__ float z_lds[EMB][8];         // 4 KB, transposed

  for (int i = threadIdx.x; i < EMB * H1_DIM; i += 512) w_lds[i] = W1[i];
  const float epsv = 1.0f + eps[0];
  const int c  = threadIdx.x & (H1_DIM - 1);
  const int rg = threadIdx.x >> 8;        // 0..1
  const int rbase = rg * 4;
  const float bc = b1[c];
  __syncthreads();

  for (int r0 = blockIdx.x * 8; r0 < N_NODES; r0 += gridDim.x * 8) {
    __syncthreads();
    for (int i = threadIdx.x; i < 8 * EMB; i += 512) {
      int rr = i >> 7;
      int k  = i & (EMB - 1);
      size_t gi = (size_t)(r0 + rr) * EMB + k;
      z_lds[k][rr] = epsv * x[gi] + aggr[gi];
    }
    __syncthreads();

    float a0 = bc, a1 = bc, a2 = bc, a3 = bc;
#pragma unroll 4
    for (int k = 0; k < EMB; k++) {
      float w = w_lds[k * H1_DIM + c];
      float4 z4 = *reinterpret_cast<const float4*>(&z_lds[k][rbase]);
      a0 += z4.x * w; a1 += z4.y * w; a2 += z4.z * w; a3 += z4.w * w;
    }
    size_t r = (size_t)(r0 + rbase);
    h1[(r + 0) * H1_DIM + c] = a0;
    h1[(r + 1) * H1_DIM + c] = a1;
    h1[(r + 2) * H1_DIM + c] = a2;
    h1[(r + 3) * H1_DIM + c] = a3;
  }
}

// ---------------- column stats (sum, sumsq) ----------------
__global__ void colstats_kernel(const float* __restrict__ h, int ncols,
                                float* __restrict__ sum, float* __restrict__ sumsq) {
  const int c = threadIdx.x;
  float s = 0.0f, q = 0.0f;
  for (int r = blockIdx.x; r < N_NODES; r += gridDim.x) {
    float v = h[(size_t)r * ncols + c];
    s += v;
    q += v * v;
  }
  atomicAdd(&sum[c], s);
  atomicAdd(&sumsq[c], q);
}

// a = gamma * rsqrt(var + eps); cc = beta - mu * a
__global__ void finalize_stats_kernel(const float* __restrict__ sum,
                                      const float* __restrict__ sumsq,
                                      const float* __restrict__ gamma,
                                      const float* __restrict__ beta,
                                      float* __restrict__ a, float* __restrict__ cc,
                                      int ncols, float inv_n) {
  int c = threadIdx.x;
  if (c < ncols) {
    float mu  = sum[c] * inv_n;
    float var = sumsq[c] * inv_n - mu * mu;
    float rs  = rsqrtf(var + BN_EPS);
    float ai  = rs * gamma[c];
    a[c]  = ai;
    cc[c] = beta[c] - mu * ai;
  }
}

// ---------------- GEMM2: h2 = relu(bn1(h1)) @ W2 + b2 ----------------
__global__ __launch_bounds__(512) void gemm2_kernel(const float* __restrict__ h1,
                                                    const float* __restrict__ a1,
                                                    const float* __restrict__ c1,
                                                    const float* __restrict__ W2,
                                                    const float* __restrict__ b2,
                                                    float* __restrict__ h2) {
  __shared__ float w_lds[H1_DIM * EMB];   // 128 KB
  __shared__ float u_lds[H1_DIM][8];      // 8 KB, transposed

  for (int i = threadIdx.x; i < H1_DIM * EMB; i += 512) w_lds[i] = W2[i];
  const int c  = threadIdx.x & (EMB - 1);
  const int rg = threadIdx.x >> 7;        // 0..3
  const int rbase = rg * 2;
  const float bc = b2[c];
  __syncthreads();

  for (int r0 = blockIdx.x * 8; r0 < N_NODES; r0 += gridDim.x * 8) {
    __syncthreads();
    for (int i = threadIdx.x; i < 8 * H1_DIM; i += 512) {
      int rr = i >> 8;
      int k  = i & (H1_DIM - 1);
      float v = h1[(size_t)(r0 + rr) * H1_DIM + k] * a1[k] + c1[k];
      u_lds[k][rr] = v > 0.0f ? v : 0.0f;
    }
    __syncthreads();

    float acc0 = bc, acc1 = bc;
#pragma unroll 4
    for (int k = 0; k < H1_DIM; k++) {
      float w = w_lds[k * EMB + c];
      float2 u2 = *reinterpret_cast<const float2*>(&u_lds[k][rbase]);
      acc0 += u2.x * w; acc1 += u2.y * w;
    }
    size_t r = (size_t)(r0 + rbase);
    h2[(r + 0) * EMB + c] = acc0;
    h2[(r + 1) * EMB + c] = acc1;
  }
}

// ---------------- BN2 + deterministic dropout ----------------
// jax_threefry_partitionable=True (default since jax 0.4.30), x64 OFF:
// _threefry_random_bits_partitionable, bit_width=32:
//   counts = iota(u64); (w0, w1) = threefry2x32((0,42), (hi32(j), lo32(j)))
//   bits[j] = convert_element_type(w0 ^ w1, uint32)   <-- XOR combine, not truncate
// uniform f32: u = bitcast((bits>>9)|0x3F800000) - 1;  keep = u < 0.8f
__global__ void bn2_dropout_kernel(const float* __restrict__ h2,
                                   const float* __restrict__ a2,
                                   const float* __restrict__ c2,
                                   float* __restrict__ out) {
  int j = blockIdx.x * blockDim.x + threadIdx.x;
  if (j >= N_NODES * EMB) return;

  uint32_t x0 = 0u, x1 = (uint32_t)j;
  threefry2x32(0u, 42u, x0, x1);
  uint32_t bits = x0 ^ x1;

  float u = __uint_as_float((bits >> 9) | 0x3F800000u) - 1.0f;
  int c = j & (EMB - 1);
  float v = h2[j] * a2[c] + c2[c];
  out[j] = (u < 0.8f) ? v * 1.25f : 0.0f;
}

// ---------------- launch ----------------
extern "C" void kernel_launch(void* const* d_in, const int* in_sizes, int n_in,
                              void* d_out, int out_size, void* d_ws, size_t ws_size,
                              hipStream_t stream) {
  const float* x      = (const float*)d_in[0];
  const uint32_t* ei  = (const uint32_t*)d_in[1];
  const float* eattr  = (const float*)d_in[2];
  const float* W_edge = (const float*)d_in[3];
  const float* b_edge = (const float*)d_in[4];
  const float* eps    = (const float*)d_in[5];
  const float* W1     = (const float*)d_in[6];
  const float* b1     = (const float*)d_in[7];
  const float* g1     = (const float*)d_in[8];
  const float* bt1    = (const float*)d_in[9];
  const float* W2     = (const float*)d_in[10];
  const float* b2     = (const float*)d_in[11];
  const float* g2     = (const float*)d_in[12];
  const float* bt2    = (const float*)d_in[13];
  float* out = (float*)d_out;

  float* ws   = (float*)d_ws;
  float* aggr = ws;                         // 6.4M floats (25.6 MB)
  float* h1   = ws + 6400000;               // 12.8M floats (51.2 MB)
  float* h2   = aggr;                       // alias: aggr dead after gemm1
  float* st   = ws + 19200000;              // stats block
  float* s1 = st,        *q1 = st + 256,  *a1 = st + 512,  *c1 = st + 768;
  float* s2 = st + 1024, *q2 = st + 1152, *a2 = st + 1280, *c2 = st + 1408;
  int*   flag  = (int*)(st + 1520);
  // idx32 aliases the h1 region: only needed during edge_aggr, h1 written later.
  int*   idx32 = (int*)h1;

  hipMemsetAsync(aggr, 0, (size_t)6400000 * sizeof(float), stream);
  hipMemsetAsync(st, 0, 1536 * sizeof(float), stream);

  detect_idx_kernel<<<1, 64, 0, stream>>>(ei, flag);
  convert_idx_kernel<<<(2 * N_EDGES + 255) / 256, 256, 0, stream>>>(ei, flag, idx32);
  edge_aggr_kernel<<<2048, 256, 0, stream>>>(x, idx32, idx32 + N_EDGES, eattr, W_edge, b_edge, aggr);
  gemm1_kernel<<<512, 512, 0, stream>>>(x, aggr, eps, W1, b1, h1);
  colstats_kernel<<<1024, H1_DIM, 0, stream>>>(h1, H1_DIM, s1, q1);
  finalize_stats_kernel<<<1, 256, 0, stream>>>(s1, q1, g1, bt1, a1, c1, H1_DIM, 1.0f / N_NODES);
  gemm2_kernel<<<512, 512, 0, stream>>>(h1, a1, c1, W2, b2, h2);
  colstats_kernel<<<1024, EMB, 0, stream>>>(h2, EMB, s2, q2);
  finalize_stats_kernel<<<1, 128, 0, stream>>>(s2, q2, g2, bt2, a2, c2, EMB, 1.0f / N_NODES);
  bn2_dropout_kernel<<<25000, 256, 0, stream>>>(h2, a2, c2, out);
}

// Round 8
// 783.059 us; speedup vs baseline: 1.0737x; 1.0737x over previous
//
#include <hip/hip_runtime.h>
#include <cstdint>
#include <cstddef>

#define N_NODES 50000
#define N_EDGES 800000
#define EMB 128
#define EDGE_DIM 16
#define H1_DIM 256
#define BN_EPS 1e-5f

typedef float f32x2 __attribute__((ext_vector_type(2)));

// ---------------- threefry2x32 (JAX-compatible) ----------------
__device__ __forceinline__ uint32_t rotl32(uint32_t v, int n) {
  return (v << n) | (v >> (32 - n));
}

__device__ __forceinline__ void tf_round4(uint32_t& x0, uint32_t& x1,
                                          int r0, int r1, int r2, int r3) {
  x0 += x1; x1 = rotl32(x1, r0); x1 ^= x0;
  x0 += x1; x1 = rotl32(x1, r1); x1 ^= x0;
  x0 += x1; x1 = rotl32(x1, r2); x1 ^= x0;
  x0 += x1; x1 = rotl32(x1, r3); x1 ^= x0;
}

__device__ __forceinline__ void threefry2x32(uint32_t k0, uint32_t k1,
                                             uint32_t& x0, uint32_t& x1) {
  uint32_t k2 = k0 ^ k1 ^ 0x1BD11BDAu;
  x0 += k0; x1 += k1;
  tf_round4(x0, x1, 13, 15, 26, 6);  x0 += k1; x1 += k2 + 1u;
  tf_round4(x0, x1, 17, 29, 16, 24); x0 += k2; x1 += k0 + 2u;
  tf_round4(x0, x1, 13, 15, 26, 6);  x0 += k0; x1 += k1 + 3u;
  tf_round4(x0, x1, 17, 29, 16, 24); x0 += k1; x1 += k2 + 4u;
  tf_round4(x0, x1, 13, 15, 26, 6);  x0 += k2; x1 += k0 + 5u;
}

// ---------------- CSR build ----------------
__global__ void hist_kernel(const int* __restrict__ dst, int* __restrict__ cnt) {
  int e = blockIdx.x * blockDim.x + threadIdx.x;
  if (e < N_EDGES) atomicAdd(&cnt[dst[e]], 1);
}

__global__ __launch_bounds__(1024) void scan_kernel(const int* __restrict__ cnt,
                                                    int* __restrict__ offs,
                                                    int* __restrict__ cursor) {
  __shared__ int partial[1024];
  const int CH = 49;   // 1024*49 = 50176 >= N_NODES
  const int t = threadIdx.x;
  const int base = t * CH;
  int s = 0;
  for (int i = 0; i < CH; i++) {
    int idx = base + i;
    if (idx < N_NODES) s += cnt[idx];
  }
  partial[t] = s;
  __syncthreads();
  for (int off = 1; off < 1024; off <<= 1) {
    int v = partial[t];
    int u = (t >= off) ? partial[t - off] : 0;
    __syncthreads();
    partial[t] = v + u;
    __syncthreads();
  }
  int run = (t > 0) ? partial[t - 1] : 0;
  for (int i = 0; i < CH; i++) {
    int idx = base + i;
    if (idx < N_NODES) {
      offs[idx] = run;
      cursor[idx] = run;
      run += cnt[idx];
    }
  }
  if (t == 1023) offs[N_NODES] = run;   // = N_EDGES
}

__global__ void scatter_kernel(const int* __restrict__ dst,
                               int* __restrict__ cursor,
                               int* __restrict__ sorted) {
  int e = blockIdx.x * blockDim.x + threadIdx.x;
  if (e < N_EDGES) {
    int pos = atomicAdd(&cursor[dst[e]], 1);
    sorted[pos] = e;
  }
}

// ---------------- aggregate: one wave per dst node, atomic-free ----------
// z[n] = (1+eps)*x[n] + sum_{e: dst=n} relu(x[src_e] + eattr_e @ W_edge + b_edge)
__global__ __launch_bounds__(512) void aggregate_kernel(
    const float2* __restrict__ x2,
    const int* __restrict__ src,
    const float* __restrict__ eattr,
    const int* __restrict__ offs,
    const int* __restrict__ sorted,
    const float2* __restrict__ W2,   // [16][64] float2 view of [16][128]
    const float2* __restrict__ b2,   // [64]
    const float* __restrict__ eps,
    float2* __restrict__ z2) {
  __shared__ float2 w_lds[EDGE_DIM * 64];   // 8 KB
  __shared__ float2 b_lds[64];

  for (int i = threadIdx.x; i < EDGE_DIM * 64; i += 512) w_lds[i] = W2[i];
  if (threadIdx.x < 64) b_lds[threadIdx.x] = b2[threadIdx.x];
  __syncthreads();

  const int lane = threadIdx.x & 63;
  const int wid  = threadIdx.x >> 6;   // 0..7
  const int n = blockIdx.x * 8 + wid;
  if (n >= N_NODES) return;

  const float2 bv = b_lds[lane];
  float accx = 0.0f, accy = 0.0f;
  const int beg = offs[n], end = offs[n + 1];

  for (int i = beg; i < end; i++) {
    const int eid = sorted[i];
    const int s = src[eid];
    float a = (lane < EDGE_DIM) ? eattr[eid * EDGE_DIM + lane] : 0.0f;
    float ex = bv.x, ey = bv.y;
#pragma unroll
    for (int k = 0; k < EDGE_DIM; k++) {
      float ak = __shfl(a, k, 64);
      float2 wk = w_lds[k * 64 + lane];
      ex += ak * wk.x;
      ey += ak * wk.y;
    }
    float2 xv = x2[(size_t)s * 64 + lane];
    float mx = xv.x + ex; mx = mx > 0.0f ? mx : 0.0f;
    float my = xv.y + ey; my = my > 0.0f ? my : 0.0f;
    accx += mx; accy += my;
  }

  const float epsv = 1.0f + eps[0];
  float2 xn = x2[(size_t)n * 64 + lane];
  float2 zv;
  zv.x = epsv * xn.x + accx;
  zv.y = epsv * xn.y + accy;
  z2[(size_t)n * 64 + lane] = zv;
}

// ---------------- GEMM1: h1 = z @ W1 + b1 ----------------
// W1 streamed from L2; 16-row transposed z tile in LDS (stride 18,
// broadcast float2 reads). 512 thr: col=t&255, rowgroup=t>>8 (2 x 8 rows).
__global__ __launch_bounds__(512) void gemm1_kernel(
    const float* __restrict__ z,
    const float* __restrict__ W1,
    const float* __restrict__ b1,
    float* __restrict__ h1) {
  __shared__ float z_lds[EMB * 18];   // 9.2 KB

  const int c     = threadIdx.x & (H1_DIM - 1);
  const int rbase = (threadIdx.x >> 8) * 8;
  const float bc  = b1[c];

  const int r0 = blockIdx.x * 16;
  for (int i = threadIdx.x; i < 16 * EMB; i += 512) {
    int rr = i >> 7;
    int k  = i & (EMB - 1);
    z_lds[k * 18 + rr] = z[(size_t)(r0 + rr) * EMB + k];
  }
  __syncthreads();

  float acc[8];
#pragma unroll
  for (int j = 0; j < 8; j++) acc[j] = bc;

#pragma unroll 4
  for (int k = 0; k < EMB; k++) {
    float wv = W1[k * H1_DIM + c];
    const f32x2* zp = reinterpret_cast<const f32x2*>(&z_lds[k * 18 + rbase]);
    f32x2 z0 = zp[0], z1 = zp[1], z2v = zp[2], z3 = zp[3];
    acc[0] += z0.x * wv;  acc[1] += z0.y * wv;
    acc[2] += z1.x * wv;  acc[3] += z1.y * wv;
    acc[4] += z2v.x * wv; acc[5] += z2v.y * wv;
    acc[6] += z3.x * wv;  acc[7] += z3.y * wv;
  }
#pragma unroll
  for (int j = 0; j < 8; j++)
    h1[(size_t)(r0 + rbase + j) * H1_DIM + c] = acc[j];
}

// ---------------- column stats (sum, sumsq) ----------------
__global__ void colstats_kernel(const float* __restrict__ h, int ncols,
                                float* __restrict__ sum, float* __restrict__ sumsq) {
  const int c = threadIdx.x;
  float s = 0.0f, q = 0.0f;
  for (int r = blockIdx.x; r < N_NODES; r += gridDim.x) {
    float v = h[(size_t)r * ncols + c];
    s += v;
    q += v * v;
  }
  atomicAdd(&sum[c], s);
  atomicAdd(&sumsq[c], q);
}

// a = gamma * rsqrt(var + eps); cc = beta - mu * a
__global__ void finalize_stats_kernel(const float* __restrict__ sum,
                                      const float* __restrict__ sumsq,
                                      const float* __restrict__ gamma,
                                      const float* __restrict__ beta,
                                      float* __restrict__ a, float* __restrict__ cc,
                                      int ncols, float inv_n) {
  int c = threadIdx.x;
  if (c < ncols) {
    float mu  = sum[c] * inv_n;
    float var = sumsq[c] * inv_n - mu * mu;
    float rs  = rsqrtf(var + BN_EPS);
    float ai  = rs * gamma[c];
    a[c]  = ai;
    cc[c] = beta[c] - mu * ai;
  }
}

// ---------------- GEMM2: h2 = relu(bn1(h1)) @ W2 + b2 ----------------
// 256 thr: col=t&127, rowgroup=t>>7 (2 x 8 rows). W2 from L2.
__global__ __launch_bounds__(256) void gemm2_kernel(
    const float* __restrict__ h1,
    const float* __restrict__ a1,
    const float* __restrict__ c1,
    const float* __restrict__ W2,
    const float* __restrict__ b2,
    float* __restrict__ h2) {
  __shared__ float u_lds[H1_DIM * 18];   // 18.4 KB
  __shared__ float a_lds[H1_DIM];
  __shared__ float c_lds[H1_DIM];

  if (threadIdx.x < H1_DIM) {
    a_lds[threadIdx.x] = a1[threadIdx.x];
    c_lds[threadIdx.x] = c1[threadIdx.x];
  }
  const int c     = threadIdx.x & (EMB - 1);
  const int rbase = (threadIdx.x >> 7) * 8;
  const float bc  = b2[c];
  __syncthreads();

  const int r0 = blockIdx.x * 16;
  for (int i = threadIdx.x; i < 16 * H1_DIM; i += 256) {
    int rr = i >> 8;
    int k  = i & (H1_DIM - 1);
    float v = h1[(size_t)(r0 + rr) * H1_DIM + k] * a_lds[k] + c_lds[k];
    u_lds[k * 18 + rr] = v > 0.0f ? v : 0.0f;
  }
  __syncthreads();

  float acc[8];
#pragma unroll
  for (int j = 0; j < 8; j++) acc[j] = bc;

#pragma unroll 4
  for (int k = 0; k < H1_DIM; k++) {
    float wv = W2[k * EMB + c];
    const f32x2* up = reinterpret_cast<const f32x2*>(&u_lds[k * 18 + rbase]);
    f32x2 u0 = up[0], u1 = up[1], u2 = up[2], u3 = up[3];
    acc[0] += u0.x * wv; acc[1] += u0.y * wv;
    acc[2] += u1.x * wv; acc[3] += u1.y * wv;
    acc[4] += u2.x * wv; acc[5] += u2.y * wv;
    acc[6] += u3.x * wv; acc[7] += u3.y * wv;
  }
#pragma unroll
  for (int j = 0; j < 8; j++)
    h2[(size_t)(r0 + rbase + j) * EMB + c] = acc[j];
}

// ---------------- BN2 + deterministic dropout ----------------
// jax_threefry_partitionable=True, x64 off: bits[j] = w0 ^ w1 of
// threefry2x32((0,42), (0, j)); keep = bitcast((bits>>9)|0x3F800000)-1 < 0.8
__global__ void bn2_dropout_kernel(const float* __restrict__ h2,
                                   const float* __restrict__ a2,
                                   const float* __restrict__ c2,
                                   float* __restrict__ out) {
  int j = blockIdx.x * blockDim.x + threadIdx.x;
  if (j >= N_NODES * EMB) return;

  uint32_t x0 = 0u, x1 = (uint32_t)j;
  threefry2x32(0u, 42u, x0, x1);
  uint32_t bits = x0 ^ x1;

  float u = __uint_as_float((bits >> 9) | 0x3F800000u) - 1.0f;
  int c = j & (EMB - 1);
  float v = h2[j] * a2[c] + c2[c];
  out[j] = (u < 0.8f) ? v * 1.25f : 0.0f;
}

// ---------------- launch ----------------
extern "C" void kernel_launch(void* const* d_in, const int* in_sizes, int n_in,
                              void* d_out, int out_size, void* d_ws, size_t ws_size,
                              hipStream_t stream) {
  const float* x      = (const float*)d_in[0];
  const int*   ei     = (const int*)d_in[1];   // int32 storage (proven R2==R4)
  const float* eattr  = (const float*)d_in[2];
  const float* W_edge = (const float*)d_in[3];
  const float* b_edge = (const float*)d_in[4];
  const float* eps    = (const float*)d_in[5];
  const float* W1     = (const float*)d_in[6];
  const float* b1     = (const float*)d_in[7];
  const float* g1     = (const float*)d_in[8];
  const float* bt1    = (const float*)d_in[9];
  const float* W2     = (const float*)d_in[10];
  const float* b2     = (const float*)d_in[11];
  const float* g2     = (const float*)d_in[12];
  const float* bt2    = (const float*)d_in[13];
  float* out = (float*)d_out;

  const int* src = ei;
  const int* dst = ei + N_EDGES;

  float* ws = (float*)d_ws;
  float* z  = ws;                       // 6.4M floats (25.6 MB)
  float* h1 = ws + 6400000;             // 12.8M floats (51.2 MB)
  float* h2 = z;                        // alias: z dead after gemm1
  float* st = ws + 19200000;            // stats block
  float* s1 = st,        *q1 = st + 256,  *a1 = st + 512,  *c1 = st + 768;
  float* s2 = st + 1024, *q2 = st + 1152, *a2 = st + 1280, *c2 = st + 1408;

  // CSR scratch aliases the h1 region (dead until gemm1 writes it).
  int* cnt    = (int*)h1;               // 50304
  int* offs   = cnt + 50304;            // 50304
  int* cursor = offs + 50304;           // 50304
  int* sorted = cursor + 50304;         // 800000

  hipMemsetAsync(st, 0, 1536 * sizeof(float), stream);
  hipMemsetAsync(cnt, 0, 50304 * sizeof(int), stream);

  hist_kernel<<<(N_EDGES + 255) / 256, 256, 0, stream>>>(dst, cnt);
  scan_kernel<<<1, 1024, 0, stream>>>(cnt, offs, cursor);
  scatter_kernel<<<(N_EDGES + 255) / 256, 256, 0, stream>>>(dst, cursor, sorted);
  aggregate_kernel<<<6250, 512, 0, stream>>>(
      (const float2*)x, src, eattr, offs, sorted,
      (const float2*)W_edge, (const float2*)b_edge, eps, (float2*)z);
  gemm1_kernel<<<3125, 512, 0, stream>>>(z, W1, b1, h1);
  colstats_kernel<<<1024, H1_DIM, 0, stream>>>(h1, H1_DIM, s1, q1);
  finalize_stats_kernel<<<1, 256, 0, stream>>>(s1, q1, g1, bt1, a1, c1, H1_DIM, 1.0f / N_NODES);
  gemm2_kernel<<<3125, 256, 0, stream>>>(h1, a1, c1, W2, b2, h2);
  colstats_kernel<<<1024, EMB, 0, stream>>>(h2, EMB, s2, q2);
  finalize_stats_kernel<<<1, 128, 0, stream>>>(s2, q2, g2, bt2, a2, c2, EMB, 1.0f / N_NODES);
  bn2_dropout_kernel<<<25000, 256, 0, stream>>>(h2, a2, c2, out);
}

// Round 9
// 762.167 us; speedup vs baseline: 1.1032x; 1.0274x over previous
//
#include <hip/hip_runtime.h>
#include <cstdint>
#include <cstddef>

#define N_NODES 50000
#define N_EDGES 800000
#define EMB 128
#define EDGE_DIM 16
#define H1_DIM 256
#define BN_EPS 1e-5f

typedef float f32x2 __attribute__((ext_vector_type(2)));

// ---------------- threefry2x32 (JAX-compatible) ----------------
__device__ __forceinline__ uint32_t rotl32(uint32_t v, int n) {
  return (v << n) | (v >> (32 - n));
}

__device__ __forceinline__ void tf_round4(uint32_t& x0, uint32_t& x1,
                                          int r0, int r1, int r2, int r3) {
  x0 += x1; x1 = rotl32(x1, r0); x1 ^= x0;
  x0 += x1; x1 = rotl32(x1, r1); x1 ^= x0;
  x0 += x1; x1 = rotl32(x1, r2); x1 ^= x0;
  x0 += x1; x1 = rotl32(x1, r3); x1 ^= x0;
}

__device__ __forceinline__ void threefry2x32(uint32_t k0, uint32_t k1,
                                             uint32_t& x0, uint32_t& x1) {
  uint32_t k2 = k0 ^ k1 ^ 0x1BD11BDAu;
  x0 += k0; x1 += k1;
  tf_round4(x0, x1, 13, 15, 26, 6);  x0 += k1; x1 += k2 + 1u;
  tf_round4(x0, x1, 17, 29, 16, 24); x0 += k2; x1 += k0 + 2u;
  tf_round4(x0, x1, 13, 15, 26, 6);  x0 += k0; x1 += k1 + 3u;
  tf_round4(x0, x1, 17, 29, 16, 24); x0 += k1; x1 += k2 + 4u;
  tf_round4(x0, x1, 13, 15, 26, 6);  x0 += k2; x1 += k0 + 5u;
}

// ---------------- CSR build ----------------
__global__ void hist_kernel(const int* __restrict__ dst, int* __restrict__ cnt) {
  int e = blockIdx.x * blockDim.x + threadIdx.x;
  if (e < N_EDGES) atomicAdd(&cnt[dst[e]], 1);
}

__global__ __launch_bounds__(1024) void scan_kernel(const int* __restrict__ cnt,
                                                    int* __restrict__ offs,
                                                    int* __restrict__ cursor) {
  __shared__ int partial[1024];
  const int CH = 49;   // 1024*49 = 50176 >= N_NODES
  const int t = threadIdx.x;
  const int base = t * CH;
  int s = 0;
  for (int i = 0; i < CH; i++) {
    int idx = base + i;
    if (idx < N_NODES) s += cnt[idx];
  }
  partial[t] = s;
  __syncthreads();
  for (int off = 1; off < 1024; off <<= 1) {
    int v = partial[t];
    int u = (t >= off) ? partial[t - off] : 0;
    __syncthreads();
    partial[t] = v + u;
    __syncthreads();
  }
  int run = (t > 0) ? partial[t - 1] : 0;
  for (int i = 0; i < CH; i++) {
    int idx = base + i;
    if (idx < N_NODES) {
      offs[idx] = run;
      cursor[idx] = run;
      run += cnt[idx];
    }
  }
  if (t == 1023) offs[N_NODES] = run;   // = N_EDGES
}

__global__ void scatter_kernel(const int* __restrict__ dst,
                               int* __restrict__ cursor,
                               int* __restrict__ sorted) {
  int e = blockIdx.x * blockDim.x + threadIdx.x;
  if (e < N_EDGES) {
    int pos = atomicAdd(&cursor[dst[e]], 1);
    sorted[pos] = e;
  }
}

// ---------------- aggregate: one wave per dst node, atomic-free ----------
// z[n] = (1+eps)*x[n] + sum_{e: dst=n} relu(x[src_e] + eattr_e @ W_edge + b_edge)
// 4-way unrolled edge loop: 4 independent x-gathers in flight per wave
// (latency-bound fix), fused k-loop shares each w_lds read across 4 edges.
__global__ __launch_bounds__(512) void aggregate_kernel(
    const float2* __restrict__ x2,
    const int* __restrict__ src,
    const float* __restrict__ eattr,
    const int* __restrict__ offs,
    const int* __restrict__ sorted,
    const float2* __restrict__ W2,   // [16][64] float2 view of [16][128]
    const float2* __restrict__ b2,   // [64]
    const float* __restrict__ eps,
    float2* __restrict__ z2) {
  __shared__ float2 w_lds[EDGE_DIM * 64];   // 8 KB
  __shared__ float2 b_lds[64];

  for (int i = threadIdx.x; i < EDGE_DIM * 64; i += 512) w_lds[i] = W2[i];
  if (threadIdx.x < 64) b_lds[threadIdx.x] = b2[threadIdx.x];
  __syncthreads();

  const int lane = threadIdx.x & 63;
  const int wid  = threadIdx.x >> 6;   // 0..7
  const int n = blockIdx.x * 8 + wid;
  if (n >= N_NODES) return;

  const float2 bv = b_lds[lane];
  float accx = 0.0f, accy = 0.0f;
  const int beg = offs[n], end = offs[n + 1];

  int i = beg;
  for (; i + 4 <= end; i += 4) {
    const int e0 = sorted[i + 0];
    const int e1 = sorted[i + 1];
    const int e2 = sorted[i + 2];
    const int e3 = sorted[i + 3];
    const int s0 = src[e0], s1 = src[e1], s2 = src[e2], s3 = src[e3];
    // issue all 4 row-gathers early (independent, overlap latencies)
    float2 xv0 = x2[(size_t)s0 * 64 + lane];
    float2 xv1 = x2[(size_t)s1 * 64 + lane];
    float2 xv2 = x2[(size_t)s2 * 64 + lane];
    float2 xv3 = x2[(size_t)s3 * 64 + lane];
    float a0 = (lane < EDGE_DIM) ? eattr[e0 * EDGE_DIM + lane] : 0.0f;
    float a1 = (lane < EDGE_DIM) ? eattr[e1 * EDGE_DIM + lane] : 0.0f;
    float a2 = (lane < EDGE_DIM) ? eattr[e2 * EDGE_DIM + lane] : 0.0f;
    float a3 = (lane < EDGE_DIM) ? eattr[e3 * EDGE_DIM + lane] : 0.0f;

    float ex0 = bv.x, ey0 = bv.y, ex1 = bv.x, ey1 = bv.y;
    float ex2 = bv.x, ey2 = bv.y, ex3 = bv.x, ey3 = bv.y;
#pragma unroll
    for (int k = 0; k < EDGE_DIM; k++) {
      float2 wk = w_lds[k * 64 + lane];
      float ak0 = __shfl(a0, k, 64);
      float ak1 = __shfl(a1, k, 64);
      float ak2 = __shfl(a2, k, 64);
      float ak3 = __shfl(a3, k, 64);
      ex0 += ak0 * wk.x; ey0 += ak0 * wk.y;
      ex1 += ak1 * wk.x; ey1 += ak1 * wk.y;
      ex2 += ak2 * wk.x; ey2 += ak2 * wk.y;
      ex3 += ak3 * wk.x; ey3 += ak3 * wk.y;
    }
    float m;
    m = xv0.x + ex0; accx += m > 0.0f ? m : 0.0f;
    m = xv0.y + ey0; accy += m > 0.0f ? m : 0.0f;
    m = xv1.x + ex1; accx += m > 0.0f ? m : 0.0f;
    m = xv1.y + ey1; accy += m > 0.0f ? m : 0.0f;
    m = xv2.x + ex2; accx += m > 0.0f ? m : 0.0f;
    m = xv2.y + ey2; accy += m > 0.0f ? m : 0.0f;
    m = xv3.x + ex3; accx += m > 0.0f ? m : 0.0f;
    m = xv3.y + ey3; accy += m > 0.0f ? m : 0.0f;
  }
  for (; i < end; i++) {
    const int eid = sorted[i];
    const int s = src[eid];
    float a = (lane < EDGE_DIM) ? eattr[eid * EDGE_DIM + lane] : 0.0f;
    float2 xv = x2[(size_t)s * 64 + lane];
    float ex = bv.x, ey = bv.y;
#pragma unroll
    for (int k = 0; k < EDGE_DIM; k++) {
      float ak = __shfl(a, k, 64);
      float2 wk = w_lds[k * 64 + lane];
      ex += ak * wk.x;
      ey += ak * wk.y;
    }
    float mx = xv.x + ex; accx += mx > 0.0f ? mx : 0.0f;
    float my = xv.y + ey; accy += my > 0.0f ? my : 0.0f;
  }

  const float epsv = 1.0f + eps[0];
  float2 xn = x2[(size_t)n * 64 + lane];
  float2 zv;
  zv.x = epsv * xn.x + accx;
  zv.y = epsv * xn.y + accy;
  z2[(size_t)n * 64 + lane] = zv;
}

// ---------------- GEMM1: h1 = z @ W1 + b1 ----------------
// W1 streamed from L2; 16-row transposed z tile in LDS (stride 18,
// broadcast float2 reads). 512 thr: col=t&255, rowgroup=t>>8 (2 x 8 rows).
__global__ __launch_bounds__(512) void gemm1_kernel(
    const float* __restrict__ z,
    const float* __restrict__ W1,
    const float* __restrict__ b1,
    float* __restrict__ h1) {
  __shared__ float z_lds[EMB * 18];   // 9.2 KB

  const int c     = threadIdx.x & (H1_DIM - 1);
  const int rbase = (threadIdx.x >> 8) * 8;
  const float bc  = b1[c];

  const int r0 = blockIdx.x * 16;
  for (int i = threadIdx.x; i < 16 * EMB; i += 512) {
    int rr = i >> 7;
    int k  = i & (EMB - 1);
    z_lds[k * 18 + rr] = z[(size_t)(r0 + rr) * EMB + k];
  }
  __syncthreads();

  float acc[8];
#pragma unroll
  for (int j = 0; j < 8; j++) acc[j] = bc;

#pragma unroll 4
  for (int k = 0; k < EMB; k++) {
    float wv = W1[k * H1_DIM + c];
    const f32x2* zp = reinterpret_cast<const f32x2*>(&z_lds[k * 18 + rbase]);
    f32x2 z0 = zp[0], z1 = zp[1], z2v = zp[2], z3 = zp[3];
    acc[0] += z0.x * wv;  acc[1] += z0.y * wv;
    acc[2] += z1.x * wv;  acc[3] += z1.y * wv;
    acc[4] += z2v.x * wv; acc[5] += z2v.y * wv;
    acc[6] += z3.x * wv;  acc[7] += z3.y * wv;
  }
#pragma unroll
  for (int j = 0; j < 8; j++)
    h1[(size_t)(r0 + rbase + j) * H1_DIM + c] = acc[j];
}

// ---------------- column stats (sum, sumsq) ----------------
__global__ void colstats_kernel(const float* __restrict__ h, int ncols,
                                float* __restrict__ sum, float* __restrict__ sumsq) {
  const int c = threadIdx.x;
  float s = 0.0f, q = 0.0f;
  for (int r = blockIdx.x; r < N_NODES; r += gridDim.x) {
    float v = h[(size_t)r * ncols + c];
    s += v;
    q += v * v;
  }
  atomicAdd(&sum[c], s);
  atomicAdd(&sumsq[c], q);
}

// a = gamma * rsqrt(var + eps); cc = beta - mu * a
__global__ void finalize_stats_kernel(const float* __restrict__ sum,
                                      const float* __restrict__ sumsq,
                                      const float* __restrict__ gamma,
                                      const float* __restrict__ beta,
                                      float* __restrict__ a, float* __restrict__ cc,
                                      int ncols, float inv_n) {
  int c = threadIdx.x;
  if (c < ncols) {
    float mu  = sum[c] * inv_n;
    float var = sumsq[c] * inv_n - mu * mu;
    float rs  = rsqrtf(var + BN_EPS);
    float ai  = rs * gamma[c];
    a[c]  = ai;
    cc[c] = beta[c] - mu * ai;
  }
}

// ---------------- GEMM2: h2 = relu(bn1(h1)) @ W2 + b2 ----------------
// 256 thr: col=t&127, rowgroup=t>>7 (2 x 8 rows). W2 from L2.
__global__ __launch_bounds__(256) void gemm2_kernel(
    const float* __restrict__ h1,
    const float* __restrict__ a1,
    const float* __restrict__ c1,
    const float* __restrict__ W2,
    const float* __restrict__ b2,
    float* __restrict__ h2) {
  __shared__ float u_lds[H1_DIM * 18];   // 18.4 KB
  __shared__ float a_lds[H1_DIM];
  __shared__ float c_lds[H1_DIM];

  if (threadIdx.x < H1_DIM) {
    a_lds[threadIdx.x] = a1[threadIdx.x];
    c_lds[threadIdx.x] = c1[threadIdx.x];
  }
  const int c     = threadIdx.x & (EMB - 1);
  const int rbase = (threadIdx.x >> 7) * 8;
  const float bc  = b2[c];
  __syncthreads();

  const int r0 = blockIdx.x * 16;
  for (int i = threadIdx.x; i < 16 * H1_DIM; i += 256) {
    int rr = i >> 8;
    int k  = i & (H1_DIM - 1);
    float v = h1[(size_t)(r0 + rr) * H1_DIM + k] * a_lds[k] + c_lds[k];
    u_lds[k * 18 + rr] = v > 0.0f ? v : 0.0f;
  }
  __syncthreads();

  float acc[8];
#pragma unroll
  for (int j = 0; j < 8; j++) acc[j] = bc;

#pragma unroll 4
  for (int k = 0; k < H1_DIM; k++) {
    float wv = W2[k * EMB + c];
    const f32x2* up = reinterpret_cast<const f32x2*>(&u_lds[k * 18 + rbase]);
    f32x2 u0 = up[0], u1 = up[1], u2 = up[2], u3 = up[3];
    acc[0] += u0.x * wv; acc[1] += u0.y * wv;
    acc[2] += u1.x * wv; acc[3] += u1.y * wv;
    acc[4] += u2.x * wv; acc[5] += u2.y * wv;
    acc[6] += u3.x * wv; acc[7] += u3.y * wv;
  }
#pragma unroll
  for (int j = 0; j < 8; j++)
    h2[(size_t)(r0 + rbase + j) * EMB + c] = acc[j];
}

// ---------------- BN2 + deterministic dropout ----------------
// jax_threefry_partitionable=True, x64 off: bits[j] = w0 ^ w1 of
// threefry2x32((0,42), (0, j)); keep = bitcast((bits>>9)|0x3F800000)-1 < 0.8
__global__ void bn2_dropout_kernel(const float* __restrict__ h2,
                                   const float* __restrict__ a2,
                                   const float* __restrict__ c2,
                                   float* __restrict__ out) {
  int j = blockIdx.x * blockDim.x + threadIdx.x;
  if (j >= N_NODES * EMB) return;

  uint32_t x0 = 0u, x1 = (uint32_t)j;
  threefry2x32(0u, 42u, x0, x1);
  uint32_t bits = x0 ^ x1;

  float u = __uint_as_float((bits >> 9) | 0x3F800000u) - 1.0f;
  int c = j & (EMB - 1);
  float v = h2[j] * a2[c] + c2[c];
  out[j] = (u < 0.8f) ? v * 1.25f : 0.0f;
}

// ---------------- launch ----------------
extern "C" void kernel_launch(void* const* d_in, const int* in_sizes, int n_in,
                              void* d_out, int out_size, void* d_ws, size_t ws_size,
                              hipStream_t stream) {
  const float* x      = (const float*)d_in[0];
  const int*   ei     = (const int*)d_in[1];   // int32 storage (proven R2==R4)
  const float* eattr  = (const float*)d_in[2];
  const float* W_edge = (const float*)d_in[3];
  const float* b_edge = (const float*)d_in[4];
  const float* eps    = (const float*)d_in[5];
  const float* W1     = (const float*)d_in[6];
  const float* b1     = (const float*)d_in[7];
  const float* g1     = (const float*)d_in[8];
  const float* bt1    = (const float*)d_in[9];
  const float* W2     = (const float*)d_in[10];
  const float* b2     = (const float*)d_in[11];
  const float* g2     = (const float*)d_in[12];
  const float* bt2    = (const float*)d_in[13];
  float* out = (float*)d_out;

  const int* src = ei;
  const int* dst = ei + N_EDGES;

  float* ws = (float*)d_ws;
  float* z  = ws;                       // 6.4M floats (25.6 MB)
  float* h1 = ws + 6400000;             // 12.8M floats (51.2 MB)
  float* h2 = z;                        // alias: z dead after gemm1
  float* st = ws + 19200000;            // stats block
  float* s1 = st,        *q1 = st + 256,  *a1 = st + 512,  *c1 = st + 768;
  float* s2 = st + 1024, *q2 = st + 1152, *a2 = st + 1280, *c2 = st + 1408;

  // CSR scratch aliases the h1 region (dead until gemm1 writes it).
  int* cnt    = (int*)h1;               // 50304
  int* offs   = cnt + 50304;            // 50304
  int* cursor = offs + 50304;           // 50304
  int* sorted = cursor + 50304;         // 800000

  hipMemsetAsync(st, 0, 1536 * sizeof(float), stream);
  hipMemsetAsync(cnt, 0, 50304 * sizeof(int), stream);

  hist_kernel<<<(N_EDGES + 255) / 256, 256, 0, stream>>>(dst, cnt);
  scan_kernel<<<1, 1024, 0, stream>>>(cnt, offs, cursor);
  scatter_kernel<<<(N_EDGES + 255) / 256, 256, 0, stream>>>(dst, cursor, sorted);
  aggregate_kernel<<<6250, 512, 0, stream>>>(
      (const float2*)x, src, eattr, offs, sorted,
      (const float2*)W_edge, (const float2*)b_edge, eps, (float2*)z);
  gemm1_kernel<<<3125, 512, 0, stream>>>(z, W1, b1, h1);
  colstats_kernel<<<1024, H1_DIM, 0, stream>>>(h1, H1_DIM, s1, q1);
  finalize_stats_kernel<<<1, 256, 0, stream>>>(s1, q1, g1, bt1, a1, c1, H1_DIM, 1.0f / N_NODES);
  gemm2_kernel<<<3125, 256, 0, stream>>>(h1, a1, c1, W2, b2, h2);
  colstats_kernel<<<1024, EMB, 0, stream>>>(h2, EMB, s2, q2);
  finalize_stats_kernel<<<1, 128, 0, stream>>>(s2, q2, g2, bt2, a2, c2, EMB, 1.0f / N_NODES);
  bn2_dropout_kernel<<<25000, 256, 0, stream>>>(h2, a2, c2, out);
}